// Round 14
// baseline (227.715 us; speedup 1.0000x reference)
//
#include <hip/hip_runtime.h>
#include <math.h>

#define B_ 2
#define S_ 2048
#define E_ 1024
#define H_ 16
#define D_ 64
#define M_ (B_*S_)   // 4096 rows

typedef _Float16 f16x8  __attribute__((ext_vector_type(8)));
typedef _Float16 f16x4v __attribute__((ext_vector_type(4)));
typedef __fp16   h16x2  __attribute__((ext_vector_type(2)));
typedef float    f32x4  __attribute__((ext_vector_type(4)));

__device__ __forceinline__ ushort f2h(float f) {
    _Float16 h = (_Float16)f;               // RNE
    return __builtin_bit_cast(ushort, h);
}

// async global->LDS, 16B per lane; LDS dest = wave-uniform base + lane*16
__device__ __forceinline__ void gload_lds16(const ushort* g, ushort* l) {
    __builtin_amdgcn_global_load_lds(
        (const __attribute__((address_space(1))) unsigned int*)g,
        (__attribute__((address_space(3))) unsigned int*)l, 16, 0, 0);
}

// 2^x via v_exp_f32 (avoid __exp2f: glibc reserves that name)
__device__ __forceinline__ float exp2_fast(float x) {
    return __builtin_amdgcn_exp2f(x);
}

// ---------------- fused prep: W transpose+cast | x cast | RoPE table --------
__global__ void prep_kernel(const float* __restrict__ x,
                            const float* __restrict__ W0, const float* __restrict__ W1,
                            const float* __restrict__ W2, const float* __restrict__ W3,
                            ushort* __restrict__ xf, ushort* __restrict__ WT,
                            float* __restrict__ ct, float* __restrict__ st)
{
    const int bid = blockIdx.x;
    const int tid = threadIdx.x;
    __shared__ float tile[32][33];

    if (bid < 4096) {                       // ---- W transpose + f16 cast ----
        const int z = bid >> 10, rem = bid & 1023;
        const int k0 = (rem >> 5) * 32, nb = (rem & 31) * 32;
        const float* W = (z == 0) ? W0 : (z == 1) ? W1 : (z == 2) ? W2 : W3;
        const size_t zoff = (size_t)z * E_ * E_;
        const int tx = tid & 31, ty = tid >> 5;   // 32 x 8
        #pragma unroll
        for (int i = 0; i < 4; i++) {
            int r = i * 8 + ty;
            tile[r][tx] = W[(size_t)(k0 + r) * E_ + nb + tx];
        }
        __syncthreads();
        #pragma unroll
        for (int i = 0; i < 4; i++) {
            int r = i * 8 + ty;                 // local n
            WT[zoff + (size_t)(nb + r) * E_ + k0 + tx] = f2h(tile[tx][r]);
        }
    } else if (bid < 8192) {                // ---- x fp32 -> f16 ----
        const int i = (bid - 4096) * 1024 + tid * 4;
        float4 v = *(const float4*)&x[i];
        *(ushort4*)&xf[i] = make_ushort4(f2h(v.x), f2h(v.y), f2h(v.z), f2h(v.w));
    } else {                                // ---- RoPE cos/sin table ----
        const int i = (bid - 8192) * 256 + tid;   // < S_*32
        const int j = i & 31, pos = i >> 5;
        float invf = (float)pow(10000.0, -(double)j / 32.0);
        float ang  = (float)pos * invf;
        ct[i] = (float)cos((double)ang);
        st[i] = (float)sin((double)ang);
    }
}

// ---------------- f16 MFMA GEMM, DMA-ahead double-buffered ------------------
// modes: 0 = Q (bias+RoPE+0.125*log2e, f16, 16B-chunk XOR-swizzled cols),
//        1 = K (same swizzle, no scale), 2 = V (VT-fragged, 8B-chunk swizzle),
//        3 = out-proj (bias, fp32 plain)
// QKV launch: grid (8,32,3), z = mode (slowest-varying -> true mode-blocking;
// x>>3 and %3 variants interleave 3 W sets per dispatch window and thrash L2).
#define GBM 128
#define GBN 128
#define GBK 32
#define LOG2E 1.44269504088896340736f

__global__ __launch_bounds__(256, 3)
void gemm_f16(const ushort* __restrict__ A, const ushort* __restrict__ WTp,
              const float* __restrict__ b0, const float* __restrict__ b1,
              const float* __restrict__ b2,
              const float* __restrict__ ct, const float* __restrict__ st,
              ushort* __restrict__ outQ, ushort* __restrict__ outK,
              ushort* __restrict__ outV, float* __restrict__ outF,
              int force_mode)
{
    __shared__ __align__(16) ushort lA[2][GBM * GBK];   // [buf][r][k], unpadded (DMA contract)
    __shared__ __align__(16) ushort lB[2][GBN * GBK];   // W^T tile: [buf][n][k]

    const int tid  = threadIdx.x;
    const int wv   = tid >> 6, lane = tid & 63;
    const int c    = lane & 15, qd = lane >> 4;
    const int rh   = wv >> 1, chn = wv & 1;

    const int mode = (force_mode >= 0) ? force_mode : (int)blockIdx.z;
    const size_t zoff = (force_mode >= 0) ? 0 : (size_t)blockIdx.z * (E_ * E_);
    const ushort* Bt = WTp + zoff;

    const int m0 = blockIdx.y * GBM, n0 = blockIdx.x * GBN;

    const ushort* gsrc = (wv < 2) ? A : Bt;
    const int rowbase = ((wv < 2) ? m0 : n0) + (wv & 1) * 64;
    const int lofs = (wv & 1) * 64 * GBK;
    const int srow = lane >> 2;
    const int soct = (lane & 3) * 8;

    f32x4 acc[4][4] = {};

    // ---- prologue: stage k-tile 0 into buffer 0 ----
    #pragma unroll
    for (int cc = 0; cc < 4; cc++) {
        const ushort* g = gsrc + (size_t)(rowbase + cc * 16 + srow) * E_ + soct;
        gload_lds16(g, ((wv < 2) ? &lA[0][0] : &lB[0][0]) + lofs + cc * 512);
    }
    __syncthreads();

    for (int t = 0; t < E_ / GBK; t++) {
        // ---- issue k-tile t+1's DMA into the other buffer (latency hidden) ----
        if (t < E_ / GBK - 1) {
            const int nb = (t + 1) & 1;
            const int k0i = (t + 1) * GBK;
            ushort* dst = ((wv < 2) ? &lA[nb][0] : &lB[nb][0]) + lofs;
            #pragma unroll
            for (int cc = 0; cc < 4; cc++) {
                const ushort* g = gsrc + (size_t)(rowbase + cc * 16 + srow) * E_ + k0i + soct;
                gload_lds16(g, dst + cc * 512);
            }
        }

        const ushort* Ab = lA[t & 1];
        const ushort* Bb = lB[t & 1];

        f16x8 af[4], bf[4];
        #pragma unroll
        for (int mt = 0; mt < 4; mt++)
            af[mt] = *(const f16x8*)&Ab[(rh * 64 + mt * 16 + c) * GBK + qd * 8];
        #pragma unroll
        for (int nt = 0; nt < 4; nt++)
            bf[nt] = *(const f16x8*)&Bb[(chn * 64 + nt * 16 + c) * GBK + qd * 8];
        #pragma unroll
        for (int mt = 0; mt < 4; mt++)
            #pragma unroll
            for (int nt = 0; nt < 4; nt++)
                acc[mt][nt] = __builtin_amdgcn_mfma_f32_16x16x32_f16(af[mt], bf[nt], acc[mt][nt], 0, 0, 0);
        __syncthreads();   // drains t+1's DMAs, which aged a full compute phase
    }

    const float* bias = (mode == 0) ? b0 : (mode == 1) ? b1 : (mode == 2) ? b2 : b0;
    const int colbase = n0 + chn * 64;                // head-aligned (64)

    if (mode == 3) {
        #pragma unroll
        for (int mt = 0; mt < 4; mt++)
            #pragma unroll
            for (int r = 0; r < 4; r++) {
                const int row = m0 + rh * 64 + mt * 16 + qd * 4 + r;
                #pragma unroll
                for (int nt = 0; nt < 4; nt++) {
                    const int col = colbase + nt * 16 + c;
                    outF[(size_t)row * E_ + col] = acc[mt][nt][r] + bias[col];
                }
            }
    } else if (mode == 2) {
        // V^T-fragged: Vf[bh][s/128][d][(s%128)/4 ^ (d&7)][s%4], ushort units
        const int hd = colbase >> 6;
        #pragma unroll
        for (int mt = 0; mt < 4; mt++)
            #pragma unroll
            for (int r = 0; r < 4; r++) {
                const int row = m0 + rh * 64 + mt * 16 + qd * 4 + r;
                const int bb = row >> 11, sl = row & (S_ - 1);
                const int tt = sl >> 7, key = sl & 127;
                const int c4 = key >> 2, inner = key & 3;
                const size_t base = (size_t)(bb * H_ + hd) * (S_ * D_) + tt * 8192;
                #pragma unroll
                for (int nt = 0; nt < 4; nt++) {
                    const int d = nt * 16 + c;        // 0..63 within head
                    outV[base + d * 128 + ((c4 ^ (d & 7)) * 4) + inner]
                        = f2h(acc[mt][nt][r] + bias[colbase + d]);
                }
            }
    } else {
        // Q/K: RoPE pair (j, j+32); cols stored 16B-chunk-swizzled: ch' = ch ^ (row&7)
        ushort* O = (mode == 0) ? outQ : outK;
        const float sc = (mode == 0) ? 0.125f * LOG2E : 1.0f;   // exp2 path in attn
        #pragma unroll
        for (int mt = 0; mt < 4; mt++)
            #pragma unroll
            for (int r = 0; r < 4; r++) {
                const int row = m0 + rh * 64 + mt * 16 + qd * 4 + r;
                const int pos = row & (S_ - 1);
                const int sw = row & 7;
                #pragma unroll
                for (int p = 0; p < 2; p++) {
                    const int j32 = p * 16 + c;
                    const float cth = ct[pos * 32 + j32], sth = st[pos * 32 + j32];
                    const float v1 = acc[mt][p][r]     + bias[colbase + p * 16 + c];
                    const float v2 = acc[mt][p + 2][r] + bias[colbase + (p + 2) * 16 + c];
                    const float o1 = (v1 * cth - v2 * sth) * sc;   // col cd1
                    const float o2 = (v2 * cth + v1 * sth) * sc;   // col cd1+32
                    const int cd1 = p * 16 + c, cd2 = cd1 + 32;
                    O[(size_t)row * E_ + colbase + (((cd1 >> 3) ^ sw) * 8) + (cd1 & 7)] = f2h(o1);
                    O[(size_t)row * E_ + colbase + (((cd2 >> 3) ^ sw) * 8) + (cd2 & 7)] = f2h(o2);
                }
            }
    }
}

// ---------------- MFMA flash attention: 64-key tiles, 4 blocks/CU -----------
// Key-split: wave w owns keys w*16..w*16+15 of each 64-key tile, all 64
// queries -> every staged byte LDS-read once. k=16 PV MFMA: P^T already
// in-lane (S^T C-layout row qd*4+r == B-operand k-index qd*4+j). No-max
// softmax via exp2 (log2e folded into Q scale). 32 KB LDS (2x8K K + 2x8K V)
// -> 4 blocks/CU = 1024 blocks in exactly one residency round.
__global__ __launch_bounds__(256, 4)
void attn_mfma(const ushort* __restrict__ Qf, const ushort* __restrict__ Kf,
               const ushort* __restrict__ Vfg, ushort* __restrict__ ctxf)
{
    __shared__ __align__(16) ushort Kls[2][64 * 64];   // 2 x 8KB (keys x d)
    __shared__ __align__(16) ushort Vls[2][64 * 64];   // 2 x 8KB (d x 64 keys)

    const int tid = threadIdx.x;
    const int wv = tid >> 6, lane = tid & 63;
    const int c = lane & 15, qd = lane >> 4;
    const int cs = c & 7;

    // XCD swizzle: 4 bh per XCD (2MB K/V < 4MB L2/XCD)
    const int xcd = blockIdx.x & 7, ii = blockIdx.x >> 3;
    const int bh = xcd * 4 + (ii & 3);
    const int qtb = ii >> 2;
    const int b = bh >> 4, h = bh & 15;
    const int q0 = qtb * 64;

    const size_t qrow0 = (size_t)b * S_ + q0;
    const size_t krow0 = (size_t)b * S_;
    const size_t vbase = (size_t)bh * (S_ * D_);

    const int l8 = lane >> 3, l7 = lane & 7;

    // ---- stage Q tile (8KB) via DMA into Kls[0], pull B-fragments ----
    #pragma unroll
    for (int j = 0; j < 2; j++) {
        const int row = wv * 16 + j * 8 + l8;
        gload_lds16(Qf + (qrow0 + row) * E_ + h * 64 + l7 * 8,
                    &Kls[0][wv * 1024 + j * 512]);
    }
    __syncthreads();
    f16x8 qfrag[4][2];
    #pragma unroll
    for (int qt = 0; qt < 4; qt++)
        #pragma unroll
        for (int kc = 0; kc < 2; kc++)
            qfrag[qt][kc] = *(const f16x8*)&Kls[0][(qt * 16 + c) * 64 + (((kc * 4 + qd) ^ cs) * 8)];
    __syncthreads();

    f32x4 acc[4][4] = {};          // [dt][qt]: O^T partial over this wave's keys
    float lsum[4] = {0.f, 0.f, 0.f, 0.f};

    // ---- prologue: stage tile 0 into buffer 0 ----
    if (wv < 2) {                  // K keys 0..63: waves 0,1 x 32 rows
        #pragma unroll
        for (int j = 0; j < 4; j++) {
            const int row = wv * 32 + j * 8 + l8;
            gload_lds16(Kf + (krow0 + row) * E_ + h * 64 + l7 * 8,
                        &Kls[0][wv * 2048 + j * 512]);
        }
    } else {                       // V^T half-tile: 64 d-rows x 128B (keys 0..63)
        #pragma unroll
        for (int j = 0; j < 4; j++) {
            const int drow = (wv - 2) * 32 + j * 8 + l8;
            gload_lds16(Vfg + vbase + drow * 128 + l7 * 8,
                        &Vls[0][(wv - 2) * 2048 + j * 512]);
        }
    }
    __syncthreads();

    #pragma unroll 1
    for (int t = 0; t < 32; t++) {
        // ---- issue tile t+1's DMA into the other buffer (ages over compute) ----
        if (t < 31) {
            const int nb = (t + 1) & 1;
            const int k0n = (t + 1) * 64;
            const int tt = (t + 1) >> 1, half = (t + 1) & 1;
            if (wv < 2) {
                #pragma unroll
                for (int j = 0; j < 4; j++) {
                    const int row = wv * 32 + j * 8 + l8;
                    gload_lds16(Kf + (krow0 + k0n + row) * E_ + h * 64 + l7 * 8,
                                &Kls[nb][wv * 2048 + j * 512]);
                }
            } else {
                #pragma unroll
                for (int j = 0; j < 4; j++) {
                    const int drow = (wv - 2) * 32 + j * 8 + l8;
                    gload_lds16(Vfg + vbase + tt * 8192 + drow * 128 + half * 64 + l7 * 8,
                                &Vls[nb][(wv - 2) * 2048 + j * 512]);
                }
            }
        }

        const ushort* kb = Kls[t & 1];
        const ushort* vb = Vls[t & 1];

        // ---- S^T over this wave's 16 keys, exp2, pack (no cross-lane) ----
        f16x8 kfr[2];
        #pragma unroll
        for (int kc = 0; kc < 2; kc++)
            kfr[kc] = *(const f16x8*)&kb[(wv * 16 + c) * 64 + (((kc * 4 + qd) ^ cs) * 8)];

        f16x4v bfrag[4];
        #pragma unroll
        for (int qt = 0; qt < 4; qt++) {
            f32x4 s = {};
            s = __builtin_amdgcn_mfma_f32_16x16x32_f16(kfr[0], qfrag[qt][0], s, 0, 0, 0);
            s = __builtin_amdgcn_mfma_f32_16x16x32_f16(kfr[1], qfrag[qt][1], s, 0, 0, 0);
            const float p0 = exp2_fast(s[0]), p1 = exp2_fast(s[1]);
            const float p2 = exp2_fast(s[2]), p3 = exp2_fast(s[3]);
            lsum[qt] += (p0 + p1) + (p2 + p3);
            h16x2 lo = __builtin_amdgcn_cvt_pkrtz(p0, p1);
            h16x2 hi = __builtin_amdgcn_cvt_pkrtz(p2, p3);
            uint2 u;
            u.x = __builtin_bit_cast(unsigned int, lo);
            u.y = __builtin_bit_cast(unsigned int, hi);
            bfrag[qt] = __builtin_bit_cast(f16x4v, u);
        }

        // ---- O^T += V^T P^T  (k=16 MFMA, P already in-lane) ----
        #pragma unroll
        for (int dt = 0; dt < 4; dt++) {
            f16x4v vfr = *(const f16x4v*)&vb[(dt * 16 + c) * 64 + (((wv * 4 + qd) ^ cs) * 4)];
            #pragma unroll
            for (int qt = 0; qt < 4; qt++)
                acc[dt][qt] = __builtin_amdgcn_mfma_f32_16x16x16f16(vfr, bfrag[qt], acc[dt][qt], 0, 0, 0);
        }
        __syncthreads();   // publishes t+1 (its DMA aged over this compute)
    }

    // ---- cross-wave reduction (once per block) ----
    float* red = (float*)&Kls[0][0];   // 4 slots x 1024 floats = 16KB (fits)
    float* lsr = (float*)&Vls[0][0];   // 4 waves x 64 queries

    #pragma unroll
    for (int qt = 0; qt < 4; qt++) {
        float v = lsum[qt];
        v += __shfl_xor(v, 16);
        v += __shfl_xor(v, 32);
        lsum[qt] = v;
    }
    if (lane < 16) {
        #pragma unroll
        for (int qt = 0; qt < 4; qt++) lsr[wv * 64 + qt * 16 + lane] = lsum[qt];
    }

    f32x4 own[4];                  // this wave owns d-tile dt == wv
    #pragma unroll
    for (int qt = 0; qt < 4; qt++)
        own[qt] = (wv == 0) ? acc[0][qt] : (wv == 1) ? acc[1][qt]
                : (wv == 2) ? acc[2][qt] : acc[3][qt];

    #pragma unroll
    for (int r = 1; r < 4; r++) {
        const int ds = (wv + r) & 3;          // distinct slots per wave
        #pragma unroll
        for (int qt = 0; qt < 4; qt++) {
            f32x4 sv = (ds == 0) ? acc[0][qt] : (ds == 1) ? acc[1][qt]
                     : (ds == 2) ? acc[2][qt] : acc[3][qt];
            *(f32x4*)&red[ds * 1024 + qt * 256 + lane * 4] = sv;
        }
        __syncthreads();
        #pragma unroll
        for (int qt = 0; qt < 4; qt++)
            own[qt] += *(const f32x4*)&red[wv * 1024 + qt * 256 + lane * 4];
        if (r < 3) __syncthreads();
    }

    float inv[4];
    #pragma unroll
    for (int qt = 0; qt < 4; qt++) {
        const int q = qt * 16 + c;
        inv[qt] = 1.0f / (lsr[q] + lsr[64 + q] + lsr[128 + q] + lsr[192 + q]);
    }

    // store: lane holds q = qt*16+c, d = wv*16 + qd*4 + (0..3); ctx unswizzled
    const size_t obase = qrow0 * E_ + h * 64 + wv * 16 + qd * 4;
    #pragma unroll
    for (int qt = 0; qt < 4; qt++) {
        f32x4 v = own[qt];
        const float iq = inv[qt];
        ushort4 o = make_ushort4(f2h(v[0] * iq), f2h(v[1] * iq),
                                 f2h(v[2] * iq), f2h(v[3] * iq));
        *(ushort4*)&ctxf[obase + (size_t)(qt * 16 + c) * E_] = o;
    }
}

// ---------------- launch ----------------
extern "C" void kernel_launch(void* const* d_in, const int* in_sizes, int n_in,
                              void* d_out, int out_size, void* d_ws, size_t ws_size,
                              hipStream_t stream)
{
    const float* x  = (const float*)d_in[0];
    const float* Wq = (const float*)d_in[1];
    const float* bq = (const float*)d_in[2];
    const float* Wk = (const float*)d_in[3];
    const float* bk = (const float*)d_in[4];
    const float* Wv = (const float*)d_in[5];
    const float* bv = (const float*)d_in[6];
    const float* Wo = (const float*)d_in[7];
    const float* bo = (const float*)d_in[8];
    float* out = (float*)d_out;

    // ws (ushort units): Qb|Kb|Vf|xf (4M each) | WT (4x1M) | ct|st (fp32)
    // alias: ctxf -> Qb (each attn block writes exactly the Q-tile region it
    // alone reads, after its last read — no cross-block hazard)
    ushort* Qb = (ushort*)d_ws;
    ushort* Kb = Qb + (size_t)M_ * E_;
    ushort* Vf = Kb + (size_t)M_ * E_;
    ushort* xf = Vf + (size_t)M_ * E_;
    ushort* WT = xf + (size_t)M_ * E_;
    float*  ct = (float*)(WT + (size_t)4 * E_ * E_);
    float*  st = ct + S_ * 32;
    ushort* ctxf = Qb;

    hipLaunchKernelGGL(prep_kernel, dim3(8448), dim3(256), 0, stream,
                       x, Wq, Wk, Wv, Wo, xf, WT, ct, st);

    // fused QKV: grid (8,32,3), z = mode (slowest-varying: true mode-blocking)
    hipLaunchKernelGGL(gemm_f16, dim3(E_ / GBN, M_ / GBM, 3), dim3(256), 0, stream,
                       xf, WT, bq, bk, bv, ct, st,
                       Qb, Kb, Vf, (float*)nullptr, -1);

    hipLaunchKernelGGL(attn_mfma, dim3(B_ * H_ * (S_ / 64)), dim3(256), 0, stream,
                       Qb, Kb, Vf, ctxf);

    // output projection (mode 3)
    hipLaunchKernelGGL(gemm_f16, dim3(E_ / GBN, M_ / GBM), dim3(256), 0, stream,
                       ctxf, WT + (size_t)3 * E_ * E_, bo, bo, bo, ct, st,
                       (ushort*)nullptr, (ushort*)nullptr, (ushort*)nullptr, out, 3);
}

// Round 15
// 200.536 us; speedup vs baseline: 1.1355x; 1.1355x over previous
//
#include <hip/hip_runtime.h>
#include <math.h>

#define B_ 2
#define S_ 2048
#define E_ 1024
#define H_ 16
#define D_ 64
#define M_ (B_*S_)   // 4096 rows

typedef _Float16 f16x8  __attribute__((ext_vector_type(8)));
typedef _Float16 f16x4v __attribute__((ext_vector_type(4)));
typedef __fp16   h16x2  __attribute__((ext_vector_type(2)));
typedef float    f32x4  __attribute__((ext_vector_type(4)));

__device__ __forceinline__ ushort f2h(float f) {
    _Float16 h = (_Float16)f;               // RNE
    return __builtin_bit_cast(ushort, h);
}

// async global->LDS, 16B per lane; LDS dest = wave-uniform base + lane*16
__device__ __forceinline__ void gload_lds16(const ushort* g, ushort* l) {
    __builtin_amdgcn_global_load_lds(
        (const __attribute__((address_space(1))) unsigned int*)g,
        (__attribute__((address_space(3))) unsigned int*)l, 16, 0, 0);
}

// 2^x via v_exp_f32 (avoid __exp2f: glibc reserves that name)
__device__ __forceinline__ float exp2_fast(float x) {
    return __builtin_amdgcn_exp2f(x);
}

// ---------------- fused prep: W transpose+cast | x cast | RoPE table --------
__global__ void prep_kernel(const float* __restrict__ x,
                            const float* __restrict__ W0, const float* __restrict__ W1,
                            const float* __restrict__ W2, const float* __restrict__ W3,
                            ushort* __restrict__ xf, ushort* __restrict__ WT,
                            float* __restrict__ ct, float* __restrict__ st)
{
    const int bid = blockIdx.x;
    const int tid = threadIdx.x;
    __shared__ float tile[32][33];

    if (bid < 4096) {                       // ---- W transpose + f16 cast ----
        const int z = bid >> 10, rem = bid & 1023;
        const int k0 = (rem >> 5) * 32, nb = (rem & 31) * 32;
        const float* W = (z == 0) ? W0 : (z == 1) ? W1 : (z == 2) ? W2 : W3;
        const size_t zoff = (size_t)z * E_ * E_;
        const int tx = tid & 31, ty = tid >> 5;   // 32 x 8
        #pragma unroll
        for (int i = 0; i < 4; i++) {
            int r = i * 8 + ty;
            tile[r][tx] = W[(size_t)(k0 + r) * E_ + nb + tx];
        }
        __syncthreads();
        #pragma unroll
        for (int i = 0; i < 4; i++) {
            int r = i * 8 + ty;                 // local n
            WT[zoff + (size_t)(nb + r) * E_ + k0 + tx] = f2h(tile[tx][r]);
        }
    } else if (bid < 8192) {                // ---- x fp32 -> f16 ----
        const int i = (bid - 4096) * 1024 + tid * 4;
        float4 v = *(const float4*)&x[i];
        *(ushort4*)&xf[i] = make_ushort4(f2h(v.x), f2h(v.y), f2h(v.z), f2h(v.w));
    } else {                                // ---- RoPE cos/sin table ----
        const int i = (bid - 8192) * 256 + tid;   // < S_*32
        const int j = i & 31, pos = i >> 5;
        float invf = (float)pow(10000.0, -(double)j / 32.0);
        float ang  = (float)pos * invf;
        ct[i] = (float)cos((double)ang);
        st[i] = (float)sin((double)ang);
    }
}

// ---------------- f16 MFMA GEMM, DMA-ahead double-buffered ------------------
// modes: 0 = Q (bias+RoPE+0.125*log2e, f16, 16B-chunk XOR-swizzled cols),
//        1 = K (same swizzle, no scale), 2 = V (VT-fragged, 8B-chunk swizzle),
//        3 = out-proj (bias, fp32 plain)
// Grid: flat 256 blocks/mode; m_tile = bid&31, n_tile = bid>>5 so the 8
// blocks sharing an A-slab satisfy bid ≡ m (mod 8) -> same XCD -> A-slab
// fetched once per XCD (per-XCD set: 1MB A + 2MB W < 4MB L2).
#define GBM 128
#define GBN 128
#define GBK 32
#define LOG2E 1.44269504088896340736f

__global__ __launch_bounds__(256, 3)
void gemm_f16(const ushort* __restrict__ A, const ushort* __restrict__ WTp,
              const float* __restrict__ b0, const float* __restrict__ b1,
              const float* __restrict__ b2,
              const float* __restrict__ ct, const float* __restrict__ st,
              ushort* __restrict__ outQ, ushort* __restrict__ outK,
              ushort* __restrict__ outV, float* __restrict__ outF,
              int force_mode)
{
    __shared__ __align__(16) ushort lA[2][GBM * GBK];   // [buf][r][k], unpadded (DMA contract)
    __shared__ __align__(16) ushort lB[2][GBN * GBK];   // W^T tile: [buf][n][k]

    const int tid  = threadIdx.x;
    const int wv   = tid >> 6, lane = tid & 63;
    const int c    = lane & 15, qd = lane >> 4;
    const int rh   = wv >> 1, chn = wv & 1;

    const int mode = (force_mode >= 0) ? force_mode : (int)blockIdx.z;
    const size_t zoff = (force_mode >= 0) ? 0 : (size_t)blockIdx.z * (E_ * E_);
    const ushort* Bt = WTp + zoff;

    // XCD-aware flat mapping: same-m blocks land on the same XCD
    const int m0 = (blockIdx.x & 31) * GBM;
    const int n0 = (blockIdx.x >> 5) * GBN;

    const ushort* gsrc = (wv < 2) ? A : Bt;
    const int rowbase = ((wv < 2) ? m0 : n0) + (wv & 1) * 64;
    const int lofs = (wv & 1) * 64 * GBK;
    const int srow = lane >> 2;
    const int soct = (lane & 3) * 8;

    f32x4 acc[4][4] = {};

    // ---- prologue: stage k-tile 0 into buffer 0 ----
    #pragma unroll
    for (int cc = 0; cc < 4; cc++) {
        const ushort* g = gsrc + (size_t)(rowbase + cc * 16 + srow) * E_ + soct;
        gload_lds16(g, ((wv < 2) ? &lA[0][0] : &lB[0][0]) + lofs + cc * 512);
    }
    __syncthreads();

    for (int t = 0; t < E_ / GBK; t++) {
        // ---- issue k-tile t+1's DMA into the other buffer (latency hidden) ----
        if (t < E_ / GBK - 1) {
            const int nb = (t + 1) & 1;
            const int k0i = (t + 1) * GBK;
            ushort* dst = ((wv < 2) ? &lA[nb][0] : &lB[nb][0]) + lofs;
            #pragma unroll
            for (int cc = 0; cc < 4; cc++) {
                const ushort* g = gsrc + (size_t)(rowbase + cc * 16 + srow) * E_ + k0i + soct;
                gload_lds16(g, dst + cc * 512);
            }
        }

        const ushort* Ab = lA[t & 1];
        const ushort* Bb = lB[t & 1];

        f16x8 af[4], bf[4];
        #pragma unroll
        for (int mt = 0; mt < 4; mt++)
            af[mt] = *(const f16x8*)&Ab[(rh * 64 + mt * 16 + c) * GBK + qd * 8];
        #pragma unroll
        for (int nt = 0; nt < 4; nt++)
            bf[nt] = *(const f16x8*)&Bb[(chn * 64 + nt * 16 + c) * GBK + qd * 8];
        #pragma unroll
        for (int mt = 0; mt < 4; mt++)
            #pragma unroll
            for (int nt = 0; nt < 4; nt++)
                acc[mt][nt] = __builtin_amdgcn_mfma_f32_16x16x32_f16(af[mt], bf[nt], acc[mt][nt], 0, 0, 0);
        __syncthreads();   // drains t+1's DMAs, which aged a full compute phase
    }

    const float* bias = (mode == 0) ? b0 : (mode == 1) ? b1 : (mode == 2) ? b2 : b0;
    const int colbase = n0 + chn * 64;                // head-aligned (64)

    if (mode == 3) {
        #pragma unroll
        for (int mt = 0; mt < 4; mt++)
            #pragma unroll
            for (int r = 0; r < 4; r++) {
                const int row = m0 + rh * 64 + mt * 16 + qd * 4 + r;
                #pragma unroll
                for (int nt = 0; nt < 4; nt++) {
                    const int col = colbase + nt * 16 + c;
                    outF[(size_t)row * E_ + col] = acc[mt][nt][r] + bias[col];
                }
            }
    } else if (mode == 2) {
        // V^T-fragged: Vf[bh][s/128][d][(s%128)/4 ^ (d&7)][s%4], ushort units
        const int hd = colbase >> 6;
        #pragma unroll
        for (int mt = 0; mt < 4; mt++)
            #pragma unroll
            for (int r = 0; r < 4; r++) {
                const int row = m0 + rh * 64 + mt * 16 + qd * 4 + r;
                const int bb = row >> 11, sl = row & (S_ - 1);
                const int tt = sl >> 7, key = sl & 127;
                const int c4 = key >> 2, inner = key & 3;
                const size_t base = (size_t)(bb * H_ + hd) * (S_ * D_) + tt * 8192;
                #pragma unroll
                for (int nt = 0; nt < 4; nt++) {
                    const int d = nt * 16 + c;        // 0..63 within head
                    outV[base + d * 128 + ((c4 ^ (d & 7)) * 4) + inner]
                        = f2h(acc[mt][nt][r] + bias[colbase + d]);
                }
            }
    } else {
        // Q/K: RoPE pair (j, j+32); cols stored 16B-chunk-swizzled: ch' = ch ^ (row&7)
        ushort* O = (mode == 0) ? outQ : outK;
        const float sc = (mode == 0) ? 0.125f * LOG2E : 1.0f;   // exp2 path in attn
        #pragma unroll
        for (int mt = 0; mt < 4; mt++)
            #pragma unroll
            for (int r = 0; r < 4; r++) {
                const int row = m0 + rh * 64 + mt * 16 + qd * 4 + r;
                const int pos = row & (S_ - 1);
                const int sw = row & 7;
                #pragma unroll
                for (int p = 0; p < 2; p++) {
                    const int j32 = p * 16 + c;
                    const float cth = ct[pos * 32 + j32], sth = st[pos * 32 + j32];
                    const float v1 = acc[mt][p][r]     + bias[colbase + p * 16 + c];
                    const float v2 = acc[mt][p + 2][r] + bias[colbase + (p + 2) * 16 + c];
                    const float o1 = (v1 * cth - v2 * sth) * sc;   // col cd1
                    const float o2 = (v2 * cth + v1 * sth) * sc;   // col cd1+32
                    const int cd1 = p * 16 + c, cd2 = cd1 + 32;
                    O[(size_t)row * E_ + colbase + (((cd1 >> 3) ^ sw) * 8) + (cd1 & 7)] = f2h(o1);
                    O[(size_t)row * E_ + colbase + (((cd2 >> 3) ^ sw) * 8) + (cd2 & 7)] = f2h(o2);
                }
            }
    }
}

// ---------------- MFMA flash attention: 64-key tiles, 3 blocks/CU -----------
// Key-split: wave w owns keys w*16..w*16+15 of each 64-key tile, all 64
// queries -> every staged byte LDS-read once. k=16 PV MFMA: P^T already
// in-lane. No-max softmax via exp2 (log2e folded into Q scale).
// __launch_bounds__(256,3): VGPR cap ~170 >= ~150 live -> NO spill (R14's
// (256,4) capped at 128 and spilled ~21MB/dispatch to scratch).
__global__ __launch_bounds__(256, 3)
void attn_mfma(const ushort* __restrict__ Qf, const ushort* __restrict__ Kf,
               const ushort* __restrict__ Vfg, ushort* __restrict__ ctxf)
{
    __shared__ __align__(16) ushort Kls[2][64 * 64];   // 2 x 8KB (keys x d)
    __shared__ __align__(16) ushort Vls[2][64 * 64];   // 2 x 8KB (d x 64 keys)

    const int tid = threadIdx.x;
    const int wv = tid >> 6, lane = tid & 63;
    const int c = lane & 15, qd = lane >> 4;
    const int cs = c & 7;

    // XCD swizzle: 4 bh per XCD (2MB K/V < 4MB L2/XCD)
    const int xcd = blockIdx.x & 7, ii = blockIdx.x >> 3;
    const int bh = xcd * 4 + (ii & 3);
    const int qtb = ii >> 2;
    const int b = bh >> 4, h = bh & 15;
    const int q0 = qtb * 64;

    const size_t qrow0 = (size_t)b * S_ + q0;
    const size_t krow0 = (size_t)b * S_;
    const size_t vbase = (size_t)bh * (S_ * D_);

    const int l8 = lane >> 3, l7 = lane & 7;

    // ---- stage Q tile (8KB) via DMA into Kls[0], pull B-fragments ----
    #pragma unroll
    for (int j = 0; j < 2; j++) {
        const int row = wv * 16 + j * 8 + l8;
        gload_lds16(Qf + (qrow0 + row) * E_ + h * 64 + l7 * 8,
                    &Kls[0][wv * 1024 + j * 512]);
    }
    __syncthreads();
    f16x8 qfrag[4][2];
    #pragma unroll
    for (int qt = 0; qt < 4; qt++)
        #pragma unroll
        for (int kc = 0; kc < 2; kc++)
            qfrag[qt][kc] = *(const f16x8*)&Kls[0][(qt * 16 + c) * 64 + (((kc * 4 + qd) ^ cs) * 8)];
    __syncthreads();

    f32x4 acc[4][4] = {};          // [dt][qt]: O^T partial over this wave's keys
    float lsum[4] = {0.f, 0.f, 0.f, 0.f};

    // ---- prologue: stage tile 0 into buffer 0 ----
    if (wv < 2) {                  // K keys 0..63: waves 0,1 x 32 rows
        #pragma unroll
        for (int j = 0; j < 4; j++) {
            const int row = wv * 32 + j * 8 + l8;
            gload_lds16(Kf + (krow0 + row) * E_ + h * 64 + l7 * 8,
                        &Kls[0][wv * 2048 + j * 512]);
        }
    } else {                       // V^T half-tile: 64 d-rows x 128B (keys 0..63)
        #pragma unroll
        for (int j = 0; j < 4; j++) {
            const int drow = (wv - 2) * 32 + j * 8 + l8;
            gload_lds16(Vfg + vbase + drow * 128 + l7 * 8,
                        &Vls[0][(wv - 2) * 2048 + j * 512]);
        }
    }
    __syncthreads();

    #pragma unroll 1
    for (int t = 0; t < 32; t++) {
        // ---- issue tile t+1's DMA into the other buffer (ages over compute) ----
        if (t < 31) {
            const int nb = (t + 1) & 1;
            const int k0n = (t + 1) * 64;
            const int tt = (t + 1) >> 1, half = (t + 1) & 1;
            if (wv < 2) {
                #pragma unroll
                for (int j = 0; j < 4; j++) {
                    const int row = wv * 32 + j * 8 + l8;
                    gload_lds16(Kf + (krow0 + k0n + row) * E_ + h * 64 + l7 * 8,
                                &Kls[nb][wv * 2048 + j * 512]);
                }
            } else {
                #pragma unroll
                for (int j = 0; j < 4; j++) {
                    const int drow = (wv - 2) * 32 + j * 8 + l8;
                    gload_lds16(Vfg + vbase + tt * 8192 + drow * 128 + half * 64 + l7 * 8,
                                &Vls[nb][(wv - 2) * 2048 + j * 512]);
                }
            }
        }

        const ushort* kb = Kls[t & 1];
        const ushort* vb = Vls[t & 1];

        // ---- S^T over this wave's 16 keys, exp2, pack (no cross-lane) ----
        f16x8 kfr[2];
        #pragma unroll
        for (int kc = 0; kc < 2; kc++)
            kfr[kc] = *(const f16x8*)&kb[(wv * 16 + c) * 64 + (((kc * 4 + qd) ^ cs) * 8)];

        f16x4v bfrag[4];
        #pragma unroll
        for (int qt = 0; qt < 4; qt++) {
            f32x4 s = {};
            s = __builtin_amdgcn_mfma_f32_16x16x32_f16(kfr[0], qfrag[qt][0], s, 0, 0, 0);
            s = __builtin_amdgcn_mfma_f32_16x16x32_f16(kfr[1], qfrag[qt][1], s, 0, 0, 0);
            const float p0 = exp2_fast(s[0]), p1 = exp2_fast(s[1]);
            const float p2 = exp2_fast(s[2]), p3 = exp2_fast(s[3]);
            lsum[qt] += (p0 + p1) + (p2 + p3);
            h16x2 lo = __builtin_amdgcn_cvt_pkrtz(p0, p1);
            h16x2 hi = __builtin_amdgcn_cvt_pkrtz(p2, p3);
            uint2 u;
            u.x = __builtin_bit_cast(unsigned int, lo);
            u.y = __builtin_bit_cast(unsigned int, hi);
            bfrag[qt] = __builtin_bit_cast(f16x4v, u);
        }

        // ---- O^T += V^T P^T  (k=16 MFMA, P already in-lane) ----
        #pragma unroll
        for (int dt = 0; dt < 4; dt++) {
            f16x4v vfr = *(const f16x4v*)&vb[(dt * 16 + c) * 64 + (((wv * 4 + qd) ^ cs) * 4)];
            #pragma unroll
            for (int qt = 0; qt < 4; qt++)
                acc[dt][qt] = __builtin_amdgcn_mfma_f32_16x16x16f16(vfr, bfrag[qt], acc[dt][qt], 0, 0, 0);
        }
        __syncthreads();   // publishes t+1 (its DMA aged over this compute)
    }

    // ---- cross-wave reduction (once per block) ----
    float* red = (float*)&Kls[0][0];   // 4 slots x 1024 floats = 16KB (fits)
    float* lsr = (float*)&Vls[0][0];   // 4 waves x 64 queries

    #pragma unroll
    for (int qt = 0; qt < 4; qt++) {
        float v = lsum[qt];
        v += __shfl_xor(v, 16);
        v += __shfl_xor(v, 32);
        lsum[qt] = v;
    }
    if (lane < 16) {
        #pragma unroll
        for (int qt = 0; qt < 4; qt++) lsr[wv * 64 + qt * 16 + lane] = lsum[qt];
    }

    f32x4 own[4];                  // this wave owns d-tile dt == wv
    #pragma unroll
    for (int qt = 0; qt < 4; qt++)
        own[qt] = (wv == 0) ? acc[0][qt] : (wv == 1) ? acc[1][qt]
                : (wv == 2) ? acc[2][qt] : acc[3][qt];

    #pragma unroll
    for (int r = 1; r < 4; r++) {
        const int ds = (wv + r) & 3;          // distinct slots per wave
        #pragma unroll
        for (int qt = 0; qt < 4; qt++) {
            f32x4 sv = (ds == 0) ? acc[0][qt] : (ds == 1) ? acc[1][qt]
                     : (ds == 2) ? acc[2][qt] : acc[3][qt];
            *(f32x4*)&red[ds * 1024 + qt * 256 + lane * 4] = sv;
        }
        __syncthreads();
        #pragma unroll
        for (int qt = 0; qt < 4; qt++)
            own[qt] += *(const f32x4*)&red[wv * 1024 + qt * 256 + lane * 4];
        if (r < 3) __syncthreads();
    }

    float inv[4];
    #pragma unroll
    for (int qt = 0; qt < 4; qt++) {
        const int q = qt * 16 + c;
        inv[qt] = 1.0f / (lsr[q] + lsr[64 + q] + lsr[128 + q] + lsr[192 + q]);
    }

    // store: lane holds q = qt*16+c, d = wv*16 + qd*4 + (0..3); ctx unswizzled
    const size_t obase = qrow0 * E_ + h * 64 + wv * 16 + qd * 4;
    #pragma unroll
    for (int qt = 0; qt < 4; qt++) {
        f32x4 v = own[qt];
        const float iq = inv[qt];
        ushort4 o = make_ushort4(f2h(v[0] * iq), f2h(v[1] * iq),
                                 f2h(v[2] * iq), f2h(v[3] * iq));
        *(ushort4*)&ctxf[obase + (size_t)(qt * 16 + c) * E_] = o;
    }
}

// ---------------- launch ----------------
extern "C" void kernel_launch(void* const* d_in, const int* in_sizes, int n_in,
                              void* d_out, int out_size, void* d_ws, size_t ws_size,
                              hipStream_t stream)
{
    const float* x  = (const float*)d_in[0];
    const float* Wq = (const float*)d_in[1];
    const float* bq = (const float*)d_in[2];
    const float* Wk = (const float*)d_in[3];
    const float* bk = (const float*)d_in[4];
    const float* Wv = (const float*)d_in[5];
    const float* bv = (const float*)d_in[6];
    const float* Wo = (const float*)d_in[7];
    const float* bo = (const float*)d_in[8];
    float* out = (float*)d_out;

    // ws (ushort units): Qb|Kb|Vf|xf (4M each) | WT (4x1M) | ct|st (fp32)
    // alias: ctxf -> Qb (each attn block writes exactly the Q-tile region it
    // alone reads, after its last read — no cross-block hazard)
    ushort* Qb = (ushort*)d_ws;
    ushort* Kb = Qb + (size_t)M_ * E_;
    ushort* Vf = Kb + (size_t)M_ * E_;
    ushort* xf = Vf + (size_t)M_ * E_;
    ushort* WT = xf + (size_t)M_ * E_;
    float*  ct = (float*)(WT + (size_t)4 * E_ * E_);
    float*  st = ct + S_ * 32;
    ushort* ctxf = Qb;

    hipLaunchKernelGGL(prep_kernel, dim3(8448), dim3(256), 0, stream,
                       x, Wq, Wk, Wv, Wo, xf, WT, ct, st);

    // fused QKV: flat 256 blocks/mode (XCD-aware m-major), z = mode
    hipLaunchKernelGGL(gemm_f16, dim3(256, 1, 3), dim3(256), 0, stream,
                       xf, WT, bq, bk, bv, ct, st,
                       Qb, Kb, Vf, (float*)nullptr, -1);

    hipLaunchKernelGGL(attn_mfma, dim3(B_ * H_ * (S_ / 64)), dim3(256), 0, stream,
                       Qb, Kb, Vf, ctxf);

    // output projection (mode 3)
    hipLaunchKernelGGL(gemm_f16, dim3(256), dim3(256), 0, stream,
                       ctxf, WT + (size_t)3 * E_ * E_, bo, bo, bo, ct, st,
                       (ushort*)nullptr, (ushort*)nullptr, (ushort*)nullptr, out, 3);
}

// Round 16
// 195.396 us; speedup vs baseline: 1.1654x; 1.0263x over previous
//
#include <hip/hip_runtime.h>
#include <math.h>

#define B_ 2
#define S_ 2048
#define E_ 1024
#define H_ 16
#define D_ 64
#define M_ (B_*S_)   // 4096 rows

typedef _Float16 f16x8  __attribute__((ext_vector_type(8)));
typedef _Float16 f16x4v __attribute__((ext_vector_type(4)));
typedef __fp16   h16x2  __attribute__((ext_vector_type(2)));
typedef float    f32x4  __attribute__((ext_vector_type(4)));

__device__ __forceinline__ ushort f2h(float f) {
    _Float16 h = (_Float16)f;               // RNE
    return __builtin_bit_cast(ushort, h);
}

// async global->LDS, 16B per lane; LDS dest = wave-uniform base + lane*16
__device__ __forceinline__ void gload_lds16(const ushort* g, ushort* l) {
    __builtin_amdgcn_global_load_lds(
        (const __attribute__((address_space(1))) unsigned int*)g,
        (__attribute__((address_space(3))) unsigned int*)l, 16, 0, 0);
}

// 2^x via v_exp_f32 (avoid __exp2f: glibc reserves that name)
__device__ __forceinline__ float exp2_fast(float x) {
    return __builtin_amdgcn_exp2f(x);
}

// ---------------- fused prep: W transpose+cast | x cast | RoPE table --------
__global__ void prep_kernel(const float* __restrict__ x,
                            const float* __restrict__ W0, const float* __restrict__ W1,
                            const float* __restrict__ W2, const float* __restrict__ W3,
                            ushort* __restrict__ xf, ushort* __restrict__ WT,
                            float* __restrict__ ct, float* __restrict__ st)
{
    const int bid = blockIdx.x;
    const int tid = threadIdx.x;
    __shared__ float tile[32][33];

    if (bid < 4096) {                       // ---- W transpose + f16 cast ----
        const int z = bid >> 10, rem = bid & 1023;
        const int k0 = (rem >> 5) * 32, nb = (rem & 31) * 32;
        const float* W = (z == 0) ? W0 : (z == 1) ? W1 : (z == 2) ? W2 : W3;
        const size_t zoff = (size_t)z * E_ * E_;
        const int tx = tid & 31, ty = tid >> 5;   // 32 x 8
        #pragma unroll
        for (int i = 0; i < 4; i++) {
            int r = i * 8 + ty;
            tile[r][tx] = W[(size_t)(k0 + r) * E_ + nb + tx];
        }
        __syncthreads();
        #pragma unroll
        for (int i = 0; i < 4; i++) {
            int r = i * 8 + ty;                 // local n
            WT[zoff + (size_t)(nb + r) * E_ + k0 + tx] = f2h(tile[tx][r]);
        }
    } else if (bid < 8192) {                // ---- x fp32 -> f16 ----
        const int i = (bid - 4096) * 1024 + tid * 4;
        float4 v = *(const float4*)&x[i];
        *(ushort4*)&xf[i] = make_ushort4(f2h(v.x), f2h(v.y), f2h(v.z), f2h(v.w));
    } else {                                // ---- RoPE cos/sin table ----
        const int i = (bid - 8192) * 256 + tid;   // < S_*32
        const int j = i & 31, pos = i >> 5;
        float invf = (float)pow(10000.0, -(double)j / 32.0);
        float ang  = (float)pos * invf;
        ct[i] = (float)cos((double)ang);
        st[i] = (float)sin((double)ang);
    }
}

// ---------------- f16 MFMA GEMM, DMA-ahead double-buffered ------------------
// modes: 0 = Q (bias+RoPE+0.125*log2e, f16, 16B-chunk XOR-swizzled cols),
//        1 = K (same swizzle, no scale),
//        2 = V (regrouped: Vf[bh][t(32)][kq(4)][d(64)][k%16] -> per-(tile,
//              key-quarter) 2KB contiguous chunk = one attn wave's strip),
//        3 = out-proj (bias, fp32 plain)
// Grid: flat 256 blocks/mode; m_tile = bid&31, n_tile = bid>>5 -> same-A-slab
// blocks land on the same XCD (R15: -6us).
#define GBM 128
#define GBN 128
#define GBK 32
#define LOG2E 1.44269504088896340736f

__global__ __launch_bounds__(256, 3)
void gemm_f16(const ushort* __restrict__ A, const ushort* __restrict__ WTp,
              const float* __restrict__ b0, const float* __restrict__ b1,
              const float* __restrict__ b2,
              const float* __restrict__ ct, const float* __restrict__ st,
              ushort* __restrict__ outQ, ushort* __restrict__ outK,
              ushort* __restrict__ outV, float* __restrict__ outF,
              int force_mode)
{
    __shared__ __align__(16) ushort lA[2][GBM * GBK];   // [buf][r][k], unpadded (DMA contract)
    __shared__ __align__(16) ushort lB[2][GBN * GBK];   // W^T tile: [buf][n][k]

    const int tid  = threadIdx.x;
    const int wv   = tid >> 6, lane = tid & 63;
    const int c    = lane & 15, qd = lane >> 4;
    const int rh   = wv >> 1, chn = wv & 1;

    const int mode = (force_mode >= 0) ? force_mode : (int)blockIdx.z;
    const size_t zoff = (force_mode >= 0) ? 0 : (size_t)blockIdx.z * (E_ * E_);
    const ushort* Bt = WTp + zoff;

    // XCD-aware flat mapping: same-m blocks land on the same XCD
    const int m0 = (blockIdx.x & 31) * GBM;
    const int n0 = (blockIdx.x >> 5) * GBN;

    const ushort* gsrc = (wv < 2) ? A : Bt;
    const int rowbase = ((wv < 2) ? m0 : n0) + (wv & 1) * 64;
    const int lofs = (wv & 1) * 64 * GBK;
    const int srow = lane >> 2;
    const int soct = (lane & 3) * 8;

    f32x4 acc[4][4] = {};

    // ---- prologue: stage k-tile 0 into buffer 0 ----
    #pragma unroll
    for (int cc = 0; cc < 4; cc++) {
        const ushort* g = gsrc + (size_t)(rowbase + cc * 16 + srow) * E_ + soct;
        gload_lds16(g, ((wv < 2) ? &lA[0][0] : &lB[0][0]) + lofs + cc * 512);
    }
    __syncthreads();

    for (int t = 0; t < E_ / GBK; t++) {
        // ---- issue k-tile t+1's DMA into the other buffer (latency hidden) ----
        if (t < E_ / GBK - 1) {
            const int nb = (t + 1) & 1;
            const int k0i = (t + 1) * GBK;
            ushort* dst = ((wv < 2) ? &lA[nb][0] : &lB[nb][0]) + lofs;
            #pragma unroll
            for (int cc = 0; cc < 4; cc++) {
                const ushort* g = gsrc + (size_t)(rowbase + cc * 16 + srow) * E_ + k0i + soct;
                gload_lds16(g, dst + cc * 512);
            }
        }

        const ushort* Ab = lA[t & 1];
        const ushort* Bb = lB[t & 1];

        f16x8 af[4], bf[4];
        #pragma unroll
        for (int mt = 0; mt < 4; mt++)
            af[mt] = *(const f16x8*)&Ab[(rh * 64 + mt * 16 + c) * GBK + qd * 8];
        #pragma unroll
        for (int nt = 0; nt < 4; nt++)
            bf[nt] = *(const f16x8*)&Bb[(chn * 64 + nt * 16 + c) * GBK + qd * 8];
        #pragma unroll
        for (int mt = 0; mt < 4; mt++)
            #pragma unroll
            for (int nt = 0; nt < 4; nt++)
                acc[mt][nt] = __builtin_amdgcn_mfma_f32_16x16x32_f16(af[mt], bf[nt], acc[mt][nt], 0, 0, 0);
        __syncthreads();   // drains t+1's DMAs, which aged a full compute phase
    }

    const float* bias = (mode == 0) ? b0 : (mode == 1) ? b1 : (mode == 2) ? b2 : b0;
    const int colbase = n0 + chn * 64;                // head-aligned (64)

    if (mode == 3) {
        #pragma unroll
        for (int mt = 0; mt < 4; mt++)
            #pragma unroll
            for (int r = 0; r < 4; r++) {
                const int row = m0 + rh * 64 + mt * 16 + qd * 4 + r;
                #pragma unroll
                for (int nt = 0; nt < 4; nt++) {
                    const int col = colbase + nt * 16 + c;
                    outF[(size_t)row * E_ + col] = acc[mt][nt][r] + bias[col];
                }
            }
    } else if (mode == 2) {
        // V regrouped: Vf[bh][t][kq][d][k%16] (per-wave 2KB contiguous strips)
        const int hd = colbase >> 6;
        #pragma unroll
        for (int mt = 0; mt < 4; mt++)
            #pragma unroll
            for (int r = 0; r < 4; r++) {
                const int row = m0 + rh * 64 + mt * 16 + qd * 4 + r;
                const int bb = row >> 11, sl = row & (S_ - 1);
                const size_t base = (size_t)(bb * H_ + hd) * (S_ * D_)
                                  + (sl >> 6) * 4096 + ((sl >> 4) & 3) * 1024 + (sl & 15);
                #pragma unroll
                for (int nt = 0; nt < 4; nt++) {
                    const int d = nt * 16 + c;        // 0..63 within head
                    outV[base + d * 16] = f2h(acc[mt][nt][r] + bias[colbase + d]);
                }
            }
    } else {
        // Q/K: RoPE pair (j, j+32); cols stored 16B-chunk-swizzled: ch' = ch ^ (row&7)
        ushort* O = (mode == 0) ? outQ : outK;
        const float sc = (mode == 0) ? 0.125f * LOG2E : 1.0f;   // exp2 path in attn
        #pragma unroll
        for (int mt = 0; mt < 4; mt++)
            #pragma unroll
            for (int r = 0; r < 4; r++) {
                const int row = m0 + rh * 64 + mt * 16 + qd * 4 + r;
                const int pos = row & (S_ - 1);
                const int sw = row & 7;
                #pragma unroll
                for (int p = 0; p < 2; p++) {
                    const int j32 = p * 16 + c;
                    const float cth = ct[pos * 32 + j32], sth = st[pos * 32 + j32];
                    const float v1 = acc[mt][p][r]     + bias[colbase + p * 16 + c];
                    const float v2 = acc[mt][p + 2][r] + bias[colbase + (p + 2) * 16 + c];
                    const float o1 = (v1 * cth - v2 * sth) * sc;   // col cd1
                    const float o2 = (v2 * cth + v1 * sth) * sc;   // col cd1+32
                    const int cd1 = p * 16 + c, cd2 = cd1 + 32;
                    O[(size_t)row * E_ + colbase + (((cd1 >> 3) ^ sw) * 8) + (cd1 & 7)] = f2h(o1);
                    O[(size_t)row * E_ + colbase + (((cd2 >> 3) ^ sw) * 8) + (cd2 & 7)] = f2h(o2);
                }
            }
    }
}

// ---------------- MFMA flash attention: BARRIER-FREE k-loop -----------------
// Key-split: wave w owns keys w*16..+15 of each 64-key tile. Each wave
// DMA-stages ONLY what it consumes (its 16 K rows + its 2KB V strip) into a
// private 8KB LDS region (2-deep dbuf) -> zero __syncthreads in the loop.
// Pipeline: issue t+1's 4 DMAs -> s_waitcnt vmcnt(4) (drains t's, keeps t+1
// in flight - the hipBLASLt never-vmcnt(0) pattern) -> compute t.
// k=16 PV MFMA keeps P in-lane; no-max softmax via exp2.
__global__ __launch_bounds__(256, 3)
void attn_mfma(const ushort* __restrict__ Qf, const ushort* __restrict__ Kf,
               const ushort* __restrict__ Vfg, ushort* __restrict__ ctxf)
{
    __shared__ __align__(16) ushort L[16384];   // 32KB: 4 waves x (2 bufs x (K 2KB | V 2KB))

    const int tid = threadIdx.x;
    const int wv = tid >> 6, lane = tid & 63;
    const int c = lane & 15, qd = lane >> 4;
    const int cs = c & 7;

    // XCD swizzle: 4 bh per XCD (2MB K/V < 4MB L2/XCD)
    const int xcd = blockIdx.x & 7, ii = blockIdx.x >> 3;
    const int bh = xcd * 4 + (ii & 3);
    const int qtb = ii >> 2;
    const int b = bh >> 4, h = bh & 15;
    const int q0 = qtb * 64;

    const size_t qrow0 = (size_t)b * S_ + q0;
    const size_t krow0 = (size_t)b * S_;
    const size_t vbase = (size_t)bh * (S_ * D_);

    const int l8 = lane >> 3, l7 = lane & 7;

    // ---- stage Q tile (8KB) cooperatively, pull B-fragments ----
    #pragma unroll
    for (int j = 0; j < 2; j++) {
        const int row = wv * 16 + j * 8 + l8;
        gload_lds16(Qf + (qrow0 + row) * E_ + h * 64 + l7 * 8, &L[wv * 1024 + j * 512]);
    }
    __syncthreads();
    f16x8 qfrag[4][2];
    #pragma unroll
    for (int qt = 0; qt < 4; qt++)
        #pragma unroll
        for (int kc = 0; kc < 2; kc++)
            qfrag[qt][kc] = *(const f16x8*)&L[(qt * 16 + c) * 64 + (((kc * 4 + qd) ^ cs) * 8)];
    __syncthreads();

    f32x4 acc[4][4] = {};          // [dt][qt]: O^T partial over this wave's keys
    float lsum[4] = {0.f, 0.f, 0.f, 0.f};

    ushort* const myL = &L[wv * 4096];      // private 8KB region

    // ---- prologue: this wave stages ITS tile-0 strips into buf 0 ----
    #pragma unroll
    for (int j = 0; j < 2; j++)
        gload_lds16(Kf + (krow0 + wv * 16 + j * 8 + l8) * E_ + h * 64 + l7 * 8,
                    myL + j * 512);
    #pragma unroll
    for (int j = 0; j < 2; j++)
        gload_lds16(Vfg + vbase + wv * 1024 + j * 512 + lane * 8,
                    myL + 1024 + j * 512);

    #pragma unroll 1
    for (int t = 0; t < 32; t++) {
        // ---- issue t+1's 4 DMAs into the other private buffer ----
        if (t < 31) {
            ushort* nb = myL + ((t + 1) & 1) * 2048;
            const int k0n = (t + 1) * 64;
            #pragma unroll
            for (int j = 0; j < 2; j++)
                gload_lds16(Kf + (krow0 + k0n + wv * 16 + j * 8 + l8) * E_ + h * 64 + l7 * 8,
                            nb + j * 512);
            #pragma unroll
            for (int j = 0; j < 2; j++)
                gload_lds16(Vfg + vbase + (t + 1) * 4096 + wv * 1024 + j * 512 + lane * 8,
                            nb + 1024 + j * 512);
            __builtin_amdgcn_s_waitcnt(0x0F74);   // vmcnt(4): t's 4 done, t+1 in flight
        } else {
            __builtin_amdgcn_s_waitcnt(0x0F70);   // vmcnt(0): last tile fully landed
        }

        const ushort* kb = myL + (t & 1) * 2048;
        const ushort* vb = kb + 1024;

        // ---- S^T over this wave's 16 keys, exp2, pack (no cross-lane) ----
        f16x8 kfr[2];
        #pragma unroll
        for (int kc = 0; kc < 2; kc++)
            kfr[kc] = *(const f16x8*)&kb[c * 64 + (((kc * 4 + qd) ^ cs) * 8)];

        f16x4v bfrag[4];
        #pragma unroll
        for (int qt = 0; qt < 4; qt++) {
            f32x4 s = {};
            s = __builtin_amdgcn_mfma_f32_16x16x32_f16(kfr[0], qfrag[qt][0], s, 0, 0, 0);
            s = __builtin_amdgcn_mfma_f32_16x16x32_f16(kfr[1], qfrag[qt][1], s, 0, 0, 0);
            const float p0 = exp2_fast(s[0]), p1 = exp2_fast(s[1]);
            const float p2 = exp2_fast(s[2]), p3 = exp2_fast(s[3]);
            lsum[qt] += (p0 + p1) + (p2 + p3);
            h16x2 lo = __builtin_amdgcn_cvt_pkrtz(p0, p1);
            h16x2 hi = __builtin_amdgcn_cvt_pkrtz(p2, p3);
            uint2 u;
            u.x = __builtin_bit_cast(unsigned int, lo);
            u.y = __builtin_bit_cast(unsigned int, hi);
            bfrag[qt] = __builtin_bit_cast(f16x4v, u);
        }

        // ---- O^T += V^T P^T  (k=16 MFMA; V strip layout [d][16 keys]) ----
        #pragma unroll
        for (int dt = 0; dt < 4; dt++) {
            f16x4v vfr = *(const f16x4v*)&vb[(dt * 16 + c) * 16 + qd * 4];
            #pragma unroll
            for (int qt = 0; qt < 4; qt++)
                acc[dt][qt] = __builtin_amdgcn_mfma_f32_16x16x16f16(vfr, bfrag[qt], acc[dt][qt], 0, 0, 0);
        }
        // NO barrier: next iter only touches this wave's private region
    }

    __syncthreads();   // all waves done computing; LDS becomes reduce scratch

    // ---- cross-wave reduction (once per block) ----
    float* red = (float*)&L[0];        // 4 slots x 1024 floats = 16KB
    float* lsr = (float*)&L[8192];     // bytes 16K..17K: 4 waves x 64 queries

    #pragma unroll
    for (int qt = 0; qt < 4; qt++) {
        float v = lsum[qt];
        v += __shfl_xor(v, 16);
        v += __shfl_xor(v, 32);
        lsum[qt] = v;
    }
    if (lane < 16) {
        #pragma unroll
        for (int qt = 0; qt < 4; qt++) lsr[wv * 64 + qt * 16 + lane] = lsum[qt];
    }

    f32x4 own[4];                  // this wave owns d-tile dt == wv
    #pragma unroll
    for (int qt = 0; qt < 4; qt++)
        own[qt] = (wv == 0) ? acc[0][qt] : (wv == 1) ? acc[1][qt]
                : (wv == 2) ? acc[2][qt] : acc[3][qt];

    #pragma unroll
    for (int r = 1; r < 4; r++) {
        const int ds = (wv + r) & 3;          // distinct slots per wave
        #pragma unroll
        for (int qt = 0; qt < 4; qt++) {
            f32x4 sv = (ds == 0) ? acc[0][qt] : (ds == 1) ? acc[1][qt]
                     : (ds == 2) ? acc[2][qt] : acc[3][qt];
            *(f32x4*)&red[ds * 1024 + qt * 256 + lane * 4] = sv;
        }
        __syncthreads();
        #pragma unroll
        for (int qt = 0; qt < 4; qt++)
            own[qt] += *(const f32x4*)&red[wv * 1024 + qt * 256 + lane * 4];
        if (r < 3) __syncthreads();
    }

    float inv[4];
    #pragma unroll
    for (int qt = 0; qt < 4; qt++) {
        const int q = qt * 16 + c;
        inv[qt] = 1.0f / (lsr[q] + lsr[64 + q] + lsr[128 + q] + lsr[192 + q]);
    }

    // store: lane holds q = qt*16+c, d = wv*16 + qd*4 + (0..3); ctx unswizzled
    const size_t obase = qrow0 * E_ + h * 64 + wv * 16 + qd * 4;
    #pragma unroll
    for (int qt = 0; qt < 4; qt++) {
        f32x4 v = own[qt];
        const float iq = inv[qt];
        ushort4 o = make_ushort4(f2h(v[0] * iq), f2h(v[1] * iq),
                                 f2h(v[2] * iq), f2h(v[3] * iq));
        *(ushort4*)&ctxf[obase + (size_t)(qt * 16 + c) * E_] = o;
    }
}

// ---------------- launch ----------------
extern "C" void kernel_launch(void* const* d_in, const int* in_sizes, int n_in,
                              void* d_out, int out_size, void* d_ws, size_t ws_size,
                              hipStream_t stream)
{
    const float* x  = (const float*)d_in[0];
    const float* Wq = (const float*)d_in[1];
    const float* bq = (const float*)d_in[2];
    const float* Wk = (const float*)d_in[3];
    const float* bk = (const float*)d_in[4];
    const float* Wv = (const float*)d_in[5];
    const float* bv = (const float*)d_in[6];
    const float* Wo = (const float*)d_in[7];
    const float* bo = (const float*)d_in[8];
    float* out = (float*)d_out;

    // ws (ushort units): Qb|Kb|Vf|xf (4M each) | WT (4x1M) | ct|st (fp32)
    // alias: ctxf -> Qb (each attn block writes exactly the Q-tile region it
    // alone reads, after its last read — no cross-block hazard)
    ushort* Qb = (ushort*)d_ws;
    ushort* Kb = Qb + (size_t)M_ * E_;
    ushort* Vf = Kb + (size_t)M_ * E_;
    ushort* xf = Vf + (size_t)M_ * E_;
    ushort* WT = xf + (size_t)M_ * E_;
    float*  ct = (float*)(WT + (size_t)4 * E_ * E_);
    float*  st = ct + S_ * 32;
    ushort* ctxf = Qb;

    hipLaunchKernelGGL(prep_kernel, dim3(8448), dim3(256), 0, stream,
                       x, Wq, Wk, Wv, Wo, xf, WT, ct, st);

    // fused QKV: flat 256 blocks/mode (XCD-aware m-major), z = mode
    hipLaunchKernelGGL(gemm_f16, dim3(256, 1, 3), dim3(256), 0, stream,
                       xf, WT, bq, bk, bv, ct, st,
                       Qb, Kb, Vf, (float*)nullptr, -1);

    hipLaunchKernelGGL(attn_mfma, dim3(B_ * H_ * (S_ / 64)), dim3(256), 0, stream,
                       Qb, Kb, Vf, ctxf);

    // output projection (mode 3)
    hipLaunchKernelGGL(gemm_f16, dim3(256), dim3(256), 0, stream,
                       ctxf, WT + (size_t)3 * E_ * E_, bo, bo, bo, ct, st,
                       (ushort*)nullptr, (ushort*)nullptr, (ushort*)nullptr, out, 3);
}

// Round 17
// 190.017 us; speedup vs baseline: 1.1984x; 1.0283x over previous
//
#include <hip/hip_runtime.h>
#include <math.h>

#define B_ 2
#define S_ 2048
#define E_ 1024
#define H_ 16
#define D_ 64
#define M_ (B_*S_)   // 4096 rows

typedef _Float16 f16x8  __attribute__((ext_vector_type(8)));
typedef _Float16 f16x4v __attribute__((ext_vector_type(4)));
typedef __fp16   h16x2  __attribute__((ext_vector_type(2)));
typedef float    f32x4  __attribute__((ext_vector_type(4)));

__device__ __forceinline__ ushort f2h(float f) {
    _Float16 h = (_Float16)f;               // RNE
    return __builtin_bit_cast(ushort, h);
}

// async global->LDS, 16B per lane; LDS dest = wave-uniform base + lane*16
__device__ __forceinline__ void gload_lds16(const ushort* g, ushort* l) {
    __builtin_amdgcn_global_load_lds(
        (const __attribute__((address_space(1))) unsigned int*)g,
        (__attribute__((address_space(3))) unsigned int*)l, 16, 0, 0);
}

// 2^x via v_exp_f32 (avoid __exp2f: glibc reserves that name)
__device__ __forceinline__ float exp2_fast(float x) {
    return __builtin_amdgcn_exp2f(x);
}

// ---------------- fused prep: W transpose+cast | x cast | RoPE table --------
__global__ void prep_kernel(const float* __restrict__ x,
                            const float* __restrict__ W0, const float* __restrict__ W1,
                            const float* __restrict__ W2, const float* __restrict__ W3,
                            ushort* __restrict__ xf, ushort* __restrict__ WT,
                            float* __restrict__ ct, float* __restrict__ st)
{
    const int bid = blockIdx.x;
    const int tid = threadIdx.x;
    __shared__ float tile[32][33];

    if (bid < 4096) {                       // ---- W transpose + f16 cast ----
        const int z = bid >> 10, rem = bid & 1023;
        const int k0 = (rem >> 5) * 32, nb = (rem & 31) * 32;
        const float* W = (z == 0) ? W0 : (z == 1) ? W1 : (z == 2) ? W2 : W3;
        const size_t zoff = (size_t)z * E_ * E_;
        const int tx = tid & 31, ty = tid >> 5;   // 32 x 8
        #pragma unroll
        for (int i = 0; i < 4; i++) {
            int r = i * 8 + ty;
            tile[r][tx] = W[(size_t)(k0 + r) * E_ + nb + tx];
        }
        __syncthreads();
        #pragma unroll
        for (int i = 0; i < 4; i++) {
            int r = i * 8 + ty;                 // local n
            WT[zoff + (size_t)(nb + r) * E_ + k0 + tx] = f2h(tile[tx][r]);
        }
    } else if (bid < 8192) {                // ---- x fp32 -> f16 ----
        const int i = (bid - 4096) * 1024 + tid * 4;
        float4 v = *(const float4*)&x[i];
        *(ushort4*)&xf[i] = make_ushort4(f2h(v.x), f2h(v.y), f2h(v.z), f2h(v.w));
    } else {                                // ---- RoPE cos/sin table ----
        const int i = (bid - 8192) * 256 + tid;   // < S_*32
        const int j = i & 31, pos = i >> 5;
        float invf = (float)pow(10000.0, -(double)j / 32.0);
        float ang  = (float)pos * invf;
        ct[i] = (float)cos((double)ang);
        st[i] = (float)sin((double)ang);
    }
}

// ---------------- f16 MFMA GEMM: 3-buffer pipeline, raw-barrier K-loop ------
// modes: 0 = Q (bias+RoPE+0.125*log2e, f16, 16B-chunk XOR-swizzled cols),
//        1 = K (same swizzle, no scale),
//        2 = V (regrouped: Vf[bh][t(32)][kq(4)][d(64)][k%16]),
//        3 = out-proj (bias, fp32 plain)
// K-loop (hipBLASLt pattern): iter t issues tile t+2's DMAs, computes tile t,
// then s_waitcnt vmcnt(4) (t+1 landed, t+2 STILL IN FLIGHT - never vmcnt(0))
// + raw s_barrier. Buffer (t+2)%3 was last read at iter t-1, which every wave
// finished before the barrier admitting iter t -> no hazard.
// Grid: flat 256 blocks/mode; m_tile = bid&31, n_tile = bid>>5 (XCD-aware).
#define GBM 128
#define GBN 128
#define GBK 32
#define LOG2E 1.44269504088896340736f

__global__ __launch_bounds__(256, 3)
void gemm_f16(const ushort* __restrict__ A, const ushort* __restrict__ WTp,
              const float* __restrict__ b0, const float* __restrict__ b1,
              const float* __restrict__ b2,
              const float* __restrict__ ct, const float* __restrict__ st,
              ushort* __restrict__ outQ, ushort* __restrict__ outK,
              ushort* __restrict__ outV, float* __restrict__ outF,
              int force_mode)
{
    __shared__ __align__(16) ushort lA[3][GBM * GBK];   // [buf][r][k], unpadded (DMA contract)
    __shared__ __align__(16) ushort lB[3][GBN * GBK];   // W^T tile: [buf][n][k]

    const int tid  = threadIdx.x;
    const int wv   = tid >> 6, lane = tid & 63;
    const int c    = lane & 15, qd = lane >> 4;
    const int rh   = wv >> 1, chn = wv & 1;

    const int mode = (force_mode >= 0) ? force_mode : (int)blockIdx.z;
    const size_t zoff = (force_mode >= 0) ? 0 : (size_t)blockIdx.z * (E_ * E_);
    const ushort* Bt = WTp + zoff;

    // XCD-aware flat mapping: same-m blocks land on the same XCD
    const int m0 = (blockIdx.x & 31) * GBM;
    const int n0 = (blockIdx.x >> 5) * GBN;

    const ushort* gsrc = (wv < 2) ? A : Bt;
    const int rowbase = ((wv < 2) ? m0 : n0) + (wv & 1) * 64;
    const int lofs = (wv & 1) * 64 * GBK;
    const int srow = lane >> 2;
    const int soct = (lane & 3) * 8;

    f32x4 acc[4][4] = {};

    // ---- prologue: stage tiles 0 and 1 into buffers 0 and 1 ----
    #pragma unroll
    for (int pt = 0; pt < 2; pt++) {
        ushort* dst = ((wv < 2) ? &lA[pt][0] : &lB[pt][0]) + lofs;
        const int k0i = pt * GBK;
        #pragma unroll
        for (int cc = 0; cc < 4; cc++) {
            const ushort* g = gsrc + (size_t)(rowbase + cc * 16 + srow) * E_ + k0i + soct;
            gload_lds16(g, dst + cc * 512);
        }
    }
    __builtin_amdgcn_s_waitcnt(0x0F74);   // vmcnt(4): tile0 landed, tile1 flying
    __builtin_amdgcn_s_barrier();

    for (int t = 0; t < E_ / GBK; t++) {
        // ---- issue tile t+2's DMA (kept in flight across the barrier) ----
        if (t + 2 < E_ / GBK) {
            const int bi = (t + 2) % 3;
            const int k0i = (t + 2) * GBK;
            ushort* dst = ((wv < 2) ? &lA[bi][0] : &lB[bi][0]) + lofs;
            #pragma unroll
            for (int cc = 0; cc < 4; cc++) {
                const ushort* g = gsrc + (size_t)(rowbase + cc * 16 + srow) * E_ + k0i + soct;
                gload_lds16(g, dst + cc * 512);
            }
        }

        const ushort* Ab = lA[t % 3];
        const ushort* Bb = lB[t % 3];

        f16x8 af[4], bf[4];
        #pragma unroll
        for (int mt = 0; mt < 4; mt++)
            af[mt] = *(const f16x8*)&Ab[(rh * 64 + mt * 16 + c) * GBK + qd * 8];
        #pragma unroll
        for (int nt = 0; nt < 4; nt++)
            bf[nt] = *(const f16x8*)&Bb[(chn * 64 + nt * 16 + c) * GBK + qd * 8];
        #pragma unroll
        for (int mt = 0; mt < 4; mt++)
            #pragma unroll
            for (int nt = 0; nt < 4; nt++)
                acc[mt][nt] = __builtin_amdgcn_mfma_f32_16x16x32_f16(af[mt], bf[nt], acc[mt][nt], 0, 0, 0);

        // ---- publish t+1 without draining t+2 ----
        if (t < E_ / GBK - 2) {
            __builtin_amdgcn_s_waitcnt(0x0F74);   // vmcnt(4): t+1 landed
            __builtin_amdgcn_s_barrier();
        } else if (t == E_ / GBK - 2) {
            __builtin_amdgcn_s_waitcnt(0x0F70);   // vmcnt(0): last tile landed
            __builtin_amdgcn_s_barrier();
        }
    }

    const float* bias = (mode == 0) ? b0 : (mode == 1) ? b1 : (mode == 2) ? b2 : b0;
    const int colbase = n0 + chn * 64;                // head-aligned (64)

    if (mode == 3) {
        #pragma unroll
        for (int mt = 0; mt < 4; mt++)
            #pragma unroll
            for (int r = 0; r < 4; r++) {
                const int row = m0 + rh * 64 + mt * 16 + qd * 4 + r;
                #pragma unroll
                for (int nt = 0; nt < 4; nt++) {
                    const int col = colbase + nt * 16 + c;
                    outF[(size_t)row * E_ + col] = acc[mt][nt][r] + bias[col];
                }
            }
    } else if (mode == 2) {
        // V regrouped: Vf[bh][t][kq][d][k%16] (per-wave 2KB contiguous strips)
        const int hd = colbase >> 6;
        #pragma unroll
        for (int mt = 0; mt < 4; mt++)
            #pragma unroll
            for (int r = 0; r < 4; r++) {
                const int row = m0 + rh * 64 + mt * 16 + qd * 4 + r;
                const int bb = row >> 11, sl = row & (S_ - 1);
                const size_t base = (size_t)(bb * H_ + hd) * (S_ * D_)
                                  + (sl >> 6) * 4096 + ((sl >> 4) & 3) * 1024 + (sl & 15);
                #pragma unroll
                for (int nt = 0; nt < 4; nt++) {
                    const int d = nt * 16 + c;        // 0..63 within head
                    outV[base + d * 16] = f2h(acc[mt][nt][r] + bias[colbase + d]);
                }
            }
    } else {
        // Q/K: RoPE pair (j, j+32); cols stored 16B-chunk-swizzled: ch' = ch ^ (row&7)
        ushort* O = (mode == 0) ? outQ : outK;
        const float sc = (mode == 0) ? 0.125f * LOG2E : 1.0f;   // exp2 path in attn
        #pragma unroll
        for (int mt = 0; mt < 4; mt++)
            #pragma unroll
            for (int r = 0; r < 4; r++) {
                const int row = m0 + rh * 64 + mt * 16 + qd * 4 + r;
                const int pos = row & (S_ - 1);
                const int sw = row & 7;
                #pragma unroll
                for (int p = 0; p < 2; p++) {
                    const int j32 = p * 16 + c;
                    const float cth = ct[pos * 32 + j32], sth = st[pos * 32 + j32];
                    const float v1 = acc[mt][p][r]     + bias[colbase + p * 16 + c];
                    const float v2 = acc[mt][p + 2][r] + bias[colbase + (p + 2) * 16 + c];
                    const float o1 = (v1 * cth - v2 * sth) * sc;   // col cd1
                    const float o2 = (v2 * cth + v1 * sth) * sc;   // col cd1+32
                    const int cd1 = p * 16 + c, cd2 = cd1 + 32;
                    O[(size_t)row * E_ + colbase + (((cd1 >> 3) ^ sw) * 8) + (cd1 & 7)] = f2h(o1);
                    O[(size_t)row * E_ + colbase + (((cd2 >> 3) ^ sw) * 8) + (cd2 & 7)] = f2h(o2);
                }
            }
    }
}

// ---------------- MFMA flash attention: BARRIER-FREE k-loop (R16 winner) ----
__global__ __launch_bounds__(256, 3)
void attn_mfma(const ushort* __restrict__ Qf, const ushort* __restrict__ Kf,
               const ushort* __restrict__ Vfg, ushort* __restrict__ ctxf)
{
    __shared__ __align__(16) ushort L[16384];   // 32KB: 4 waves x (2 bufs x (K 2KB | V 2KB))

    const int tid = threadIdx.x;
    const int wv = tid >> 6, lane = tid & 63;
    const int c = lane & 15, qd = lane >> 4;
    const int cs = c & 7;

    // XCD swizzle: 4 bh per XCD (2MB K/V < 4MB L2/XCD)
    const int xcd = blockIdx.x & 7, ii = blockIdx.x >> 3;
    const int bh = xcd * 4 + (ii & 3);
    const int qtb = ii >> 2;
    const int b = bh >> 4, h = bh & 15;
    const int q0 = qtb * 64;

    const size_t qrow0 = (size_t)b * S_ + q0;
    const size_t krow0 = (size_t)b * S_;
    const size_t vbase = (size_t)bh * (S_ * D_);

    const int l8 = lane >> 3, l7 = lane & 7;

    // ---- stage Q tile (8KB) cooperatively, pull B-fragments ----
    #pragma unroll
    for (int j = 0; j < 2; j++) {
        const int row = wv * 16 + j * 8 + l8;
        gload_lds16(Qf + (qrow0 + row) * E_ + h * 64 + l7 * 8, &L[wv * 1024 + j * 512]);
    }
    __syncthreads();
    f16x8 qfrag[4][2];
    #pragma unroll
    for (int qt = 0; qt < 4; qt++)
        #pragma unroll
        for (int kc = 0; kc < 2; kc++)
            qfrag[qt][kc] = *(const f16x8*)&L[(qt * 16 + c) * 64 + (((kc * 4 + qd) ^ cs) * 8)];
    __syncthreads();

    f32x4 acc[4][4] = {};          // [dt][qt]: O^T partial over this wave's keys
    float lsum[4] = {0.f, 0.f, 0.f, 0.f};

    ushort* const myL = &L[wv * 4096];      // private 8KB region

    // ---- prologue: this wave stages ITS tile-0 strips into buf 0 ----
    #pragma unroll
    for (int j = 0; j < 2; j++)
        gload_lds16(Kf + (krow0 + wv * 16 + j * 8 + l8) * E_ + h * 64 + l7 * 8,
                    myL + j * 512);
    #pragma unroll
    for (int j = 0; j < 2; j++)
        gload_lds16(Vfg + vbase + wv * 1024 + j * 512 + lane * 8,
                    myL + 1024 + j * 512);

    #pragma unroll 1
    for (int t = 0; t < 32; t++) {
        // ---- issue t+1's 4 DMAs into the other private buffer ----
        if (t < 31) {
            ushort* nb = myL + ((t + 1) & 1) * 2048;
            const int k0n = (t + 1) * 64;
            #pragma unroll
            for (int j = 0; j < 2; j++)
                gload_lds16(Kf + (krow0 + k0n + wv * 16 + j * 8 + l8) * E_ + h * 64 + l7 * 8,
                            nb + j * 512);
            #pragma unroll
            for (int j = 0; j < 2; j++)
                gload_lds16(Vfg + vbase + (t + 1) * 4096 + wv * 1024 + j * 512 + lane * 8,
                            nb + 1024 + j * 512);
            __builtin_amdgcn_s_waitcnt(0x0F74);   // vmcnt(4): t's 4 done, t+1 in flight
        } else {
            __builtin_amdgcn_s_waitcnt(0x0F70);   // vmcnt(0): last tile fully landed
        }

        const ushort* kb = myL + (t & 1) * 2048;
        const ushort* vb = kb + 1024;

        // ---- S^T over this wave's 16 keys, exp2, pack (no cross-lane) ----
        f16x8 kfr[2];
        #pragma unroll
        for (int kc = 0; kc < 2; kc++)
            kfr[kc] = *(const f16x8*)&kb[c * 64 + (((kc * 4 + qd) ^ cs) * 8)];

        f16x4v bfrag[4];
        #pragma unroll
        for (int qt = 0; qt < 4; qt++) {
            f32x4 s = {};
            s = __builtin_amdgcn_mfma_f32_16x16x32_f16(kfr[0], qfrag[qt][0], s, 0, 0, 0);
            s = __builtin_amdgcn_mfma_f32_16x16x32_f16(kfr[1], qfrag[qt][1], s, 0, 0, 0);
            const float p0 = exp2_fast(s[0]), p1 = exp2_fast(s[1]);
            const float p2 = exp2_fast(s[2]), p3 = exp2_fast(s[3]);
            lsum[qt] += (p0 + p1) + (p2 + p3);
            h16x2 lo = __builtin_amdgcn_cvt_pkrtz(p0, p1);
            h16x2 hi = __builtin_amdgcn_cvt_pkrtz(p2, p3);
            uint2 u;
            u.x = __builtin_bit_cast(unsigned int, lo);
            u.y = __builtin_bit_cast(unsigned int, hi);
            bfrag[qt] = __builtin_bit_cast(f16x4v, u);
        }

        // ---- O^T += V^T P^T  (k=16 MFMA; V strip layout [d][16 keys]) ----
        #pragma unroll
        for (int dt = 0; dt < 4; dt++) {
            f16x4v vfr = *(const f16x4v*)&vb[(dt * 16 + c) * 16 + qd * 4];
            #pragma unroll
            for (int qt = 0; qt < 4; qt++)
                acc[dt][qt] = __builtin_amdgcn_mfma_f32_16x16x16f16(vfr, bfrag[qt], acc[dt][qt], 0, 0, 0);
        }
        // NO barrier: next iter only touches this wave's private region
    }

    __syncthreads();   // all waves done computing; LDS becomes reduce scratch

    // ---- cross-wave reduction (once per block) ----
    float* red = (float*)&L[0];        // 4 slots x 1024 floats = 16KB
    float* lsr = (float*)&L[8192];     // bytes 16K..17K: 4 waves x 64 queries

    #pragma unroll
    for (int qt = 0; qt < 4; qt++) {
        float v = lsum[qt];
        v += __shfl_xor(v, 16);
        v += __shfl_xor(v, 32);
        lsum[qt] = v;
    }
    if (lane < 16) {
        #pragma unroll
        for (int qt = 0; qt < 4; qt++) lsr[wv * 64 + qt * 16 + lane] = lsum[qt];
    }

    f32x4 own[4];                  // this wave owns d-tile dt == wv
    #pragma unroll
    for (int qt = 0; qt < 4; qt++)
        own[qt] = (wv == 0) ? acc[0][qt] : (wv == 1) ? acc[1][qt]
                : (wv == 2) ? acc[2][qt] : acc[3][qt];

    #pragma unroll
    for (int r = 1; r < 4; r++) {
        const int ds = (wv + r) & 3;          // distinct slots per wave
        #pragma unroll
        for (int qt = 0; qt < 4; qt++) {
            f32x4 sv = (ds == 0) ? acc[0][qt] : (ds == 1) ? acc[1][qt]
                     : (ds == 2) ? acc[2][qt] : acc[3][qt];
            *(f32x4*)&red[ds * 1024 + qt * 256 + lane * 4] = sv;
        }
        __syncthreads();
        #pragma unroll
        for (int qt = 0; qt < 4; qt++)
            own[qt] += *(const f32x4*)&red[wv * 1024 + qt * 256 + lane * 4];
        if (r < 3) __syncthreads();
    }

    float inv[4];
    #pragma unroll
    for (int qt = 0; qt < 4; qt++) {
        const int q = qt * 16 + c;
        inv[qt] = 1.0f / (lsr[q] + lsr[64 + q] + lsr[128 + q] + lsr[192 + q]);
    }

    // store: lane holds q = qt*16+c, d = wv*16 + qd*4 + (0..3); ctx unswizzled
    const size_t obase = qrow0 * E_ + h * 64 + wv * 16 + qd * 4;
    #pragma unroll
    for (int qt = 0; qt < 4; qt++) {
        f32x4 v = own[qt];
        const float iq = inv[qt];
        ushort4 o = make_ushort4(f2h(v[0] * iq), f2h(v[1] * iq),
                                 f2h(v[2] * iq), f2h(v[3] * iq));
        *(ushort4*)&ctxf[obase + (size_t)(qt * 16 + c) * E_] = o;
    }
}

// ---------------- launch ----------------
extern "C" void kernel_launch(void* const* d_in, const int* in_sizes, int n_in,
                              void* d_out, int out_size, void* d_ws, size_t ws_size,
                              hipStream_t stream)
{
    const float* x  = (const float*)d_in[0];
    const float* Wq = (const float*)d_in[1];
    const float* bq = (const float*)d_in[2];
    const float* Wk = (const float*)d_in[3];
    const float* bk = (const float*)d_in[4];
    const float* Wv = (const float*)d_in[5];
    const float* bv = (const float*)d_in[6];
    const float* Wo = (const float*)d_in[7];
    const float* bo = (const float*)d_in[8];
    float* out = (float*)d_out;

    // ws (ushort units): Qb|Kb|Vf|xf (4M each) | WT (4x1M) | ct|st (fp32)
    // alias: ctxf -> Qb (each attn block writes exactly the Q-tile region it
    // alone reads, after its last read — no cross-block hazard)
    ushort* Qb = (ushort*)d_ws;
    ushort* Kb = Qb + (size_t)M_ * E_;
    ushort* Vf = Kb + (size_t)M_ * E_;
    ushort* xf = Vf + (size_t)M_ * E_;
    ushort* WT = xf + (size_t)M_ * E_;
    float*  ct = (float*)(WT + (size_t)4 * E_ * E_);
    float*  st = ct + S_ * 32;
    ushort* ctxf = Qb;

    hipLaunchKernelGGL(prep_kernel, dim3(8448), dim3(256), 0, stream,
                       x, Wq, Wk, Wv, Wo, xf, WT, ct, st);

    // fused QKV: flat 256 blocks/mode (XCD-aware m-major), z = mode
    hipLaunchKernelGGL(gemm_f16, dim3(256, 1, 3), dim3(256), 0, stream,
                       xf, WT, bq, bk, bv, ct, st,
                       Qb, Kb, Vf, (float*)nullptr, -1);

    hipLaunchKernelGGL(attn_mfma, dim3(B_ * H_ * (S_ / 64)), dim3(256), 0, stream,
                       Qb, Kb, Vf, ctxf);

    // output projection (mode 3)
    hipLaunchKernelGGL(gemm_f16, dim3(256), dim3(256), 0, stream,
                       ctxf, WT + (size_t)3 * E_ * E_, bo, bo, bo, ct, st,
                       (ushort*)nullptr, (ushort*)nullptr, (ushort*)nullptr, out, 3);
}